// Round 1
// baseline (180.327 us; speedup 1.0000x reference)
//
#include <hip/hip_runtime.h>
#include <hip/hip_bf16.h>

#define N_TAGS 128
#define T_LEN  256
#define BSZ    256
#define ROOT_T 126
#define END_T  127

// One block per batch element. 512 threads = 8 waves.
// Thread (g = tid>>7, j = tid&127) holds E[32g+k][j] = exp(lt[32g+k][j]) in registers.
// Recurrence state fv[j] lives in the registers of threads 0..127.
__global__ __launch_bounds__(512) void crf_fwd_kernel(
    const float* __restrict__ feats,   // [BSZ][T_LEN][N_TAGS]
    const int*   __restrict__ tags,    // [BSZ][T_LEN]
    const int*   __restrict__ mask,    // [BSZ][T_LEN]
    const float* __restrict__ lt,      // [N_TAGS][N_TAGS]
    float*       __restrict__ per_batch) // [BSZ]
{
  const int b    = blockIdx.x;
  const int tid  = threadIdx.x;
  const int j    = tid & (N_TAGS - 1);
  const int g    = tid >> 7;      // 0..3
  const int wave = tid >> 6;      // 0..7
  const int lane = tid & 63;

  __shared__ float ps[N_TAGS];
  __shared__ float part[3 * N_TAGS];
  __shared__ float wm[2];
  __shared__ float red[12];
  __shared__ int   ired[4];

  const float* fb = feats + (size_t)b * T_LEN * N_TAGS;
  const int*   tb = tags  + b * T_LEN;

  // ---- sequence length = sum(mask[b]) (prefix mask) ----
  if (tid < T_LEN) {
    int v = mask[b * T_LEN + tid];
    #pragma unroll
    for (int d = 1; d < 64; d <<= 1) v += __shfl_xor(v, d);
    if (lane == 0) ired[wave] = v;
  }
  __syncthreads();
  const int len = ired[0] + ired[1] + ired[2] + ired[3];

  // ---- register-resident transition slice: Ereg[k] = exp(lt[32g+k][j]) ----
  float Ereg[32];
  {
    const float* p = lt + (g * 32) * N_TAGS + j;
    #pragma unroll
    for (int k = 0; k < 32; ++k) Ereg[k] = __expf(p[k * N_TAGS]);
  }

  // ---- init: fv = lt[ROOT,:] + feats[:,0,:]; prefetch feats[:,1,:] ----
  float fv = 0.0f, fnext = 0.0f;
  if (tid < N_TAGS) {
    fv    = lt[ROOT_T * N_TAGS + j] + fb[j];
    fnext = fb[N_TAGS + j];
    float mw = fv;
    #pragma unroll
    for (int d = 1; d < 64; d <<= 1) mw = fmaxf(mw, __shfl_xor(mw, d));
    if (lane == 0) wm[wave] = mw;
  }
  __syncthreads();

  // ---- forward recurrence over valid timesteps ----
  for (int t = 1; t < len; ++t) {
    const float m = fmaxf(wm[0], wm[1]);
    if (tid < N_TAGS) ps[j] = __expf(fv - m);
    __syncthreads();

    float acc = 0.0f;
    const float4* pv = (const float4*)(ps + g * 32);  // wave-uniform broadcast reads
    #pragma unroll
    for (int q = 0; q < 8; ++q) {
      const float4 p4 = pv[q];
      acc = fmaf(p4.x, Ereg[4*q+0], acc);
      acc = fmaf(p4.y, Ereg[4*q+1], acc);
      acc = fmaf(p4.z, Ereg[4*q+2], acc);
      acc = fmaf(p4.w, Ereg[4*q+3], acc);
    }
    if (tid >= N_TAGS) part[tid - N_TAGS] = acc;
    __syncthreads();

    if (tid < N_TAGS) {
      const float s = acc + part[j] + part[N_TAGS + j] + part[2 * N_TAGS + j];
      fv = m + __logf(s) + fnext;
      const int tn = (t + 1 < T_LEN) ? (t + 1) : (T_LEN - 1);
      fnext = fb[tn * N_TAGS + j];                    // prefetch next feat row
      float mw = fv;
      #pragma unroll
      for (int d = 1; d < 64; d <<= 1) mw = fmaxf(mw, __shfl_xor(mw, d));
      if (lane == 0) wm[wave] = mw;
    }
    __syncthreads();
  }

  // ---- epilogue: partition (waves 0-1) and gold-path score (waves 2-5) ----
  float x = 0.0f;
  if (tid < N_TAGS) {
    x = fv + lt[j * N_TAGS + END_T];
    float mw = x;
    #pragma unroll
    for (int d = 1; d < 64; d <<= 1) mw = fmaxf(mw, __shfl_xor(mw, d));
    if (lane == 0) red[wave] = mw;                    // red[0..1]
  } else if (tid < N_TAGS + T_LEN) {
    const int t  = tid - N_TAGS;                      // 0..255
    const int tg = tb[t];
    float c = 0.0f;
    if (t == 0)                        c += lt[ROOT_T * N_TAGS + tg];
    if (t >= 1 && t < len)             c += lt[tb[t - 1] * N_TAGS + tg];
    if (t < len && t <= T_LEN - 2)     c += fb[t * N_TAGS + tg];
    if (t == len - 1)                  c += lt[tg * N_TAGS + END_T];
    if (t == T_LEN - 1 && len == T_LEN) c += fb[t * N_TAGS + tg];
    #pragma unroll
    for (int d = 1; d < 64; d <<= 1) c += __shfl_xor(c, d);
    if (lane == 0) red[8 + (wave - 2)] = c;           // red[8..11]
  }
  __syncthreads();

  if (tid < N_TAGS) {
    const float M = fmaxf(red[0], red[1]);
    float e = __expf(x - M);
    #pragma unroll
    for (int d = 1; d < 64; d <<= 1) e += __shfl_xor(e, d);
    if (lane == 0) red[4 + wave] = e;                 // red[4..5]
  }
  __syncthreads();

  if (tid == 0) {
    const float M         = fmaxf(red[0], red[1]);
    const float partition = M + __logf(red[4] + red[5]);
    const float score     = red[8] + red[9] + red[10] + red[11];
    per_batch[b] = partition - score;
  }
}

// Deterministic final reduction: mean over 256 per-batch values.
__global__ __launch_bounds__(256) void crf_reduce_kernel(
    const float* __restrict__ per_batch, float* __restrict__ out)
{
  const int tid = threadIdx.x;
  float v = per_batch[tid] * (1.0f / BSZ);
  #pragma unroll
  for (int d = 1; d < 64; d <<= 1) v += __shfl_xor(v, d);
  __shared__ float r[4];
  if ((tid & 63) == 0) r[tid >> 6] = v;
  __syncthreads();
  if (tid == 0) out[0] = r[0] + r[1] + r[2] + r[3];
}

extern "C" void kernel_launch(void* const* d_in, const int* in_sizes, int n_in,
                              void* d_out, int out_size, void* d_ws, size_t ws_size,
                              hipStream_t stream) {
  (void)in_sizes; (void)n_in; (void)out_size; (void)ws_size;
  const float* feats = (const float*)d_in[0];
  const int*   tags  = (const int*)d_in[1];
  const int*   mask  = (const int*)d_in[2];
  const float* lt    = (const float*)d_in[3];
  float* per_batch = (float*)d_ws;   // 256 floats of scratch

  crf_fwd_kernel<<<BSZ, 512, 0, stream>>>(feats, tags, mask, lt, per_batch);
  crf_reduce_kernel<<<1, 256, 0, stream>>>(per_batch, (float*)d_out);
}

// Round 2
// 147.976 us; speedup vs baseline: 1.2186x; 1.2186x over previous
//
#include <hip/hip_runtime.h>
#include <hip/hip_bf16.h>

#define N_TAGS 128
#define T_LEN  256
#define BSZ    256
#define ROOT_T 126
#define END_T  127

typedef float f32x2 __attribute__((ext_vector_type(2)));
typedef float f32x4 __attribute__((ext_vector_type(4)));

#if __has_builtin(__builtin_elementwise_fma)
#define FMA2(a, b, c) __builtin_elementwise_fma((a), (b), (c))
#else
static __device__ __forceinline__ f32x2 FMA2(f32x2 a, f32x2 b, f32x2 c) {
  f32x2 r; r.x = fmaf(a.x, b.x, c.x); r.y = fmaf(a.y, b.y, c.y); return r;
}
#endif

// One block per batch. 128 threads = 2 waves. Thread j owns column j:
// E2[q] = {exp(lt[2q][j]), exp(lt[2q+1][j])} in 128 VGPRs, fv[j] in a register.
// One barrier per recurrence step; normalizer is fv[tag0] from 2 steps back.
__global__ __launch_bounds__(128) void crf_fwd_kernel(
    const float* __restrict__ feats,   // [BSZ][T_LEN][N_TAGS]
    const int*   __restrict__ tags,    // [BSZ][T_LEN]
    const int*   __restrict__ mask,    // [BSZ][T_LEN]
    const float* __restrict__ lt,      // [N_TAGS][N_TAGS]
    float*       __restrict__ per_batch)
{
  const int b    = blockIdx.x;
  const int tid  = threadIdx.x;        // == column j
  const int lane = tid & 63;
  const int wave = tid >> 6;

  __shared__ __align__(16) float ps[2][N_TAGS];   // double-buffered exp(fv - m)
  __shared__ __align__(16) float stage[32 * N_TAGS];
  __shared__ float wm[2];                          // fv[0] history (normalizers)
  __shared__ float red[4];
  __shared__ float sred[2];
  __shared__ int   ired[2];

  const float* fb = feats + (size_t)b * T_LEN * N_TAGS;
  const int*   tb = tags  + b * T_LEN;

  // ---- sequence length (mask is a prefix mask) ----
  {
    int v = mask[b * T_LEN + tid] + mask[b * T_LEN + N_TAGS + tid];
    #pragma unroll
    for (int d = 1; d < 64; d <<= 1) v += __shfl_xor(v, d);
    if (lane == 0) ired[wave] = v;
  }

  // ---- build register-resident E column: stage lt rows through LDS ----
  f32x2 E2[64];
  #pragma unroll
  for (int c = 0; c < 4; ++c) {
    __syncthreads();
    #pragma unroll
    for (int r = 0; r < 32; ++r)
      stage[r * N_TAGS + tid] = lt[(c * 32 + r) * N_TAGS + tid];  // coalesced
    __syncthreads();
    #pragma unroll
    for (int k = 0; k < 16; ++k) {
      f32x2 e;
      e.x = __expf(stage[(2 * k)     * N_TAGS + tid]);
      e.y = __expf(stage[(2 * k + 1) * N_TAGS + tid]);
      E2[c * 16 + k] = e;
    }
  }
  const int len = ired[0] + ired[1];
  const float ltEnd = lt[tid * N_TAGS + END_T];

  // ---- init ----
  float fv    = lt[ROOT_T * N_TAGS + tid] + fb[tid];
  float fnext = fb[N_TAGS + tid];
  if (tid == 0) wm[0] = fv;
  __syncthreads();
  float m_cur = wm[0];                  // m_1 = fv_0[0]; m_2 read in-loop from wm[0]
  ps[1][tid] = __expf(fv - m_cur);

  // ---- forward recurrence: ONE barrier per step ----
  for (int t = 1; t < len; ++t) {
    const int cur = t & 1;
    __syncthreads();                                    // ps[cur], wm[cur^1] visible
    const float m_nxt = wm[cur ^ 1];                    // fv_{t-1}[0], for NEXT ps
    const f32x4* pv = (const f32x4*)ps[cur];            // wave-uniform broadcasts
    f32x2 a0 = {0.f, 0.f}, a1 = {0.f, 0.f}, a2 = {0.f, 0.f}, a3 = {0.f, 0.f};
    #pragma unroll
    for (int q = 0; q < 16; ++q) {
      const f32x4 p = pv[2 * q];
      const f32x4 r = pv[2 * q + 1];
      f32x2 plo; plo.x = p.x; plo.y = p.y;
      f32x2 phi; phi.x = p.z; phi.y = p.w;
      f32x2 rlo; rlo.x = r.x; rlo.y = r.y;
      f32x2 rhi; rhi.x = r.z; rhi.y = r.w;
      a0 = FMA2(plo, E2[4 * q + 0], a0);
      a1 = FMA2(phi, E2[4 * q + 1], a1);
      a2 = FMA2(rlo, E2[4 * q + 2], a2);
      a3 = FMA2(rhi, E2[4 * q + 3], a3);
    }
    const float s = ((a0.x + a0.y) + (a1.x + a1.y)) + ((a2.x + a2.y) + (a3.x + a3.y));
    fv = m_cur + __logf(s) + fnext;
    const int tn = (t + 1 < T_LEN) ? (t + 1) : (T_LEN - 1);
    fnext = fb[tn * N_TAGS + tid];                      // prefetch next feat row
    ps[cur ^ 1][tid] = __expf(fv - m_nxt);
    if (tid == 0) wm[cur] = fv;                         // becomes m_{t+2}
    m_cur = m_nxt;
  }

  // ---- epilogue ----
  // partition: logsumexp_j(fv[j] + lt[j, END])
  const float x = fv + ltEnd;
  float mw = x;
  #pragma unroll
  for (int d = 1; d < 64; d <<= 1) mw = fmaxf(mw, __shfl_xor(mw, d));
  if (lane == 0) red[wave] = mw;

  // gold-path score: 2 timesteps per thread
  float c = 0.f;
  #pragma unroll
  for (int q = 0; q < 2; ++q) {
    const int t  = tid + q * N_TAGS;
    const int tg = tb[t];
    if (t == 0)                          c += lt[ROOT_T * N_TAGS + tg];
    if (t >= 1 && t < len)               c += lt[tb[t - 1] * N_TAGS + tg];
    if (t < len && t <= T_LEN - 2)       c += fb[t * N_TAGS + tg];
    if (t == len - 1)                    c += lt[tg * N_TAGS + END_T];
    if (t == T_LEN - 1 && len == T_LEN)  c += fb[t * N_TAGS + tg];
  }
  #pragma unroll
  for (int d = 1; d < 64; d <<= 1) c += __shfl_xor(c, d);
  if (lane == 0) sred[wave] = c;
  __syncthreads();

  const float M = fmaxf(red[0], red[1]);
  float e = __expf(x - M);
  #pragma unroll
  for (int d = 1; d < 64; d <<= 1) e += __shfl_xor(e, d);
  if (lane == 0) red[2 + wave] = e;
  __syncthreads();

  if (tid == 0) {
    const float partition = M + __logf(red[2] + red[3]);
    per_batch[b] = partition - (sred[0] + sred[1]);
  }
}

// Deterministic final reduction: mean over 256 per-batch values.
__global__ __launch_bounds__(256) void crf_reduce_kernel(
    const float* __restrict__ per_batch, float* __restrict__ out)
{
  const int tid = threadIdx.x;
  float v = per_batch[tid] * (1.0f / BSZ);
  #pragma unroll
  for (int d = 1; d < 64; d <<= 1) v += __shfl_xor(v, d);
  __shared__ float r[4];
  if ((tid & 63) == 0) r[tid >> 6] = v;
  __syncthreads();
  if (tid == 0) out[0] = r[0] + r[1] + r[2] + r[3];
}

extern "C" void kernel_launch(void* const* d_in, const int* in_sizes, int n_in,
                              void* d_out, int out_size, void* d_ws, size_t ws_size,
                              hipStream_t stream) {
  (void)in_sizes; (void)n_in; (void)out_size; (void)ws_size;
  const float* feats = (const float*)d_in[0];
  const int*   tags  = (const int*)d_in[1];
  const int*   mask  = (const int*)d_in[2];
  const float* lt    = (const float*)d_in[3];
  float* per_batch = (float*)d_ws;   // 256 floats of scratch

  crf_fwd_kernel<<<BSZ, 128, 0, stream>>>(feats, tags, mask, lt, per_batch);
  crf_reduce_kernel<<<1, 256, 0, stream>>>(per_batch, (float*)d_out);
}

// Round 3
// 94.922 us; speedup vs baseline: 1.8997x; 1.5589x over previous
//
#include <hip/hip_runtime.h>
#include <hip/hip_bf16.h>

#define N_TAGS 128
#define T_LEN  256
#define BSZ    256
#define ROOT_T 126
#define END_T  127

typedef float f32x2 __attribute__((ext_vector_type(2)));
typedef float f32x4 __attribute__((ext_vector_type(4)));

#if __has_builtin(__builtin_elementwise_fma)
#define FMA2(a, b, c) __builtin_elementwise_fma((a), (b), (c))
#else
static __device__ __forceinline__ f32x2 FMA2(f32x2 a, f32x2 b, f32x2 c) {
  f32x2 r; r.x = fmaf(a.x, b.x, c.x); r.y = fmaf(a.y, b.y, c.y); return r;
}
#endif

// 128-element dot of an LDS vector (read as wave-uniform f32x4 broadcasts)
// against a register-resident column/row held as 64 f32x2.
static __device__ __forceinline__ float dotE(const float* __restrict__ psb,
                                             const f32x2* __restrict__ E2) {
  const f32x4* pv = (const f32x4*)psb;
  f32x2 a0 = {0.f, 0.f}, a1 = {0.f, 0.f}, a2 = {0.f, 0.f}, a3 = {0.f, 0.f};
  #pragma unroll
  for (int q = 0; q < 16; ++q) {
    const f32x4 p = pv[2 * q];
    const f32x4 r = pv[2 * q + 1];
    f32x2 plo; plo.x = p.x; plo.y = p.y;
    f32x2 phi; phi.x = p.z; phi.y = p.w;
    f32x2 rlo; rlo.x = r.x; rlo.y = r.y;
    f32x2 rhi; rhi.x = r.z; rhi.y = r.w;
    a0 = FMA2(plo, E2[4 * q + 0], a0);
    a1 = FMA2(phi, E2[4 * q + 1], a1);
    a2 = FMA2(rlo, E2[4 * q + 2], a2);
    a3 = FMA2(rhi, E2[4 * q + 3], a3);
  }
  return ((a0.x + a0.y) + (a1.x + a1.y)) + ((a2.x + a2.y) + (a3.x + a3.y));
}

// One block per batch, 256 threads = 4 waves.
// Waves 0-1: forward recurrence, thread j owns E[:,j] (64 f32x2 VGPRs).
// Waves 2-3: backward recurrence, thread i owns E[i,:] (64 f32x2 VGPRs).
// Both advance in lockstep with ONE __syncthreads per step; meet at t=128.
// Normalizers: state[0] from ~1-2 steps back (stale-max trick; exact blocking
// entries underflow to 0 either way).
__global__ __launch_bounds__(256, 1) void crf_fwd_kernel(
    const float* __restrict__ feats,   // [BSZ][T_LEN][N_TAGS]
    const int*   __restrict__ tags,    // [BSZ][T_LEN]
    const int*   __restrict__ mask,    // [BSZ][T_LEN]
    const float* __restrict__ lt,      // [N_TAGS][N_TAGS]
    float*       __restrict__ per_batch)
{
  const int b    = blockIdx.x;
  const int tid  = threadIdx.x;
  const int lane = tid & 63;
  const int wave = tid >> 6;
  const bool fwd = (tid < N_TAGS);
  const int  j   = tid & (N_TAGS - 1);   // column (fwd) / row (bwd)

  __shared__ __align__(16) float ps_f[2][N_TAGS];
  __shared__ __align__(16) float ps_b[2][N_TAGS];
  __shared__ float stage[32 * 129];      // pad 129: conflict-free both read patterns
  __shared__ float wm_f[2], wm_b[2];
  __shared__ float bb[N_TAGS];
  __shared__ float red[8];
  __shared__ float sred[4];
  __shared__ int   ired[4];

  const float* fb = feats + (size_t)b * T_LEN * N_TAGS;
  const int*   tb = tags  + b * T_LEN;

  // ---- sequence length (prefix mask) ----
  {
    int v = mask[b * T_LEN + tid];
    #pragma unroll
    for (int d = 1; d < 64; d <<= 1) v += __shfl_xor(v, d);
    if (lane == 0) ired[wave] = v;
  }

  // ---- register-resident E (fwd: column j; bwd: row j), staged via LDS ----
  f32x2 E2[64];
  #pragma unroll
  for (int c = 0; c < 4; ++c) {
    __syncthreads();
    #pragma unroll
    for (int k = 0; k < 16; ++k) {       // cooperative coalesced stage of 32 rows
      const int r   = 2 * k + (tid >> 7);
      const int col = tid & 127;
      stage[r * 129 + col] = lt[(c * 32 + r) * N_TAGS + col];
    }
    __syncthreads();
    if (fwd) {
      #pragma unroll
      for (int k = 0; k < 16; ++k) {
        f32x2 e;
        e.x = __expf(stage[(2 * k)     * 129 + j]);
        e.y = __expf(stage[(2 * k + 1) * 129 + j]);
        E2[c * 16 + k] = e;
      }
    } else if ((j >> 5) == c) {          // my row lives in this chunk
      const int ir = j & 31;
      #pragma unroll
      for (int q = 0; q < 64; ++q) {
        f32x2 e;
        e.x = __expf(stage[ir * 129 + 2 * q]);
        e.y = __expf(stage[ir * 129 + 2 * q + 1]);
        E2[q] = e;
      }
    }
  }
  const int len = ired[0] + ired[1] + ired[2] + ired[3];
  const float ltE = lt[j * N_TAGS + END_T];

  // ---- init both directions ----
  float st, fnx;                          // state (fv or beta) + staged feat
  if (fwd) {
    st  = lt[ROOT_T * N_TAGS + j] + fb[j];   // fv_0
    fnx = fb[N_TAGS + j];                    // f_1
    if (j == 0) wm_f[0] = st;
  } else {
    st  = ltE;                               // beta_255
    fnx = fb[255 * N_TAGS + j];              // f_255 (next write's feat)
    if (j == 0) wm_b[0] = st;
  }
  __syncthreads();
  float m_cur;
  if (fwd) {
    m_cur = wm_f[0];
    ps_f[1][j] = __expf(st - m_cur);
  } else {
    m_cur = wm_b[0];
    ps_b[1][j] = __expf(st + fnx - m_cur);  // prepared for t1=256 (inactive)
  }

  // ---- lockstep bidirectional recurrence: 128 steps, 1 barrier each ----
  for (int k = 0; k < 128; ++k) {
    const int cur = (k + 1) & 1;
    __syncthreads();
    if (fwd) {                             // step t = k+1 (active iff t < len)
      const float m_nxt = wm_f[cur ^ 1];
      const float s  = dotE(ps_f[cur], E2);
      const float nf = m_cur + __logf(s) + fnx;
      if (k + 1 < len) st = nf;
      fnx = fb[(k + 2) * N_TAGS + j];      // f_{t+1}
      ps_f[cur ^ 1][j] = __expf(st - m_nxt);
      if (j == 0) wm_f[cur] = st;
      m_cur = m_nxt;
    } else {                               // step t1 = 256-k (active iff t1 < len)
      const float m_nxt = wm_b[cur ^ 1];
      const float s  = dotE(ps_b[cur], E2);
      const float nb = m_cur + __logf(s);
      if (256 - k < len) st = nb;
      const float fw = fnx;                // f_{t1-1}
      fnx = fb[(254 - k) * N_TAGS + j];    // f_{t1-2} for next step
      ps_b[cur ^ 1][j] = __expf(st + fw - m_nxt);
      if (j == 0) wm_b[cur] = st;
      m_cur = m_nxt;
    }
  }
  // fwd: st = alpha_128[j]; bwd: st = beta_128[j]

  if (!fwd) bb[j] = st;
  __syncthreads();

  // ---- gold-path score: one timestep per thread ----
  float c = 0.f;
  {
    const int t  = tid;
    const int tg = tb[t];
    if (t == 0)                           c += lt[ROOT_T * N_TAGS + tg];
    if (t >= 1 && t < len)                c += lt[tb[t - 1] * N_TAGS + tg];
    if (t < len && t <= T_LEN - 2)        c += fb[t * N_TAGS + tg];
    if (t == len - 1)                     c += lt[tg * N_TAGS + END_T];
    if (t == T_LEN - 1 && len == T_LEN)   c += fb[t * N_TAGS + tg];
  }
  #pragma unroll
  for (int d = 1; d < 64; d <<= 1) c += __shfl_xor(c, d);
  if (lane == 0) sred[wave] = c;

  // ---- partition: logsumexp_j(alpha_128[j] + beta_128[j]) on waves 0-1 ----
  float x = 0.f;
  if (fwd) {
    x = st + bb[j];
    float mw = x;
    #pragma unroll
    for (int d = 1; d < 64; d <<= 1) mw = fmaxf(mw, __shfl_xor(mw, d));
    if (lane == 0) red[wave] = mw;
  }
  __syncthreads();
  if (fwd) {
    const float M = fmaxf(red[0], red[1]);
    float e = __expf(x - M);
    #pragma unroll
    for (int d = 1; d < 64; d <<= 1) e += __shfl_xor(e, d);
    if (lane == 0) red[4 + wave] = e;
  }
  __syncthreads();

  if (tid == 0) {
    const float M         = fmaxf(red[0], red[1]);
    const float partition = M + __logf(red[4] + red[5]);
    const float score     = sred[0] + sred[1] + sred[2] + sred[3];
    per_batch[b] = partition - score;
  }
}

// Deterministic final reduction: mean over 256 per-batch values.
__global__ __launch_bounds__(256) void crf_reduce_kernel(
    const float* __restrict__ per_batch, float* __restrict__ out)
{
  const int tid = threadIdx.x;
  float v = per_batch[tid] * (1.0f / BSZ);
  #pragma unroll
  for (int d = 1; d < 64; d <<= 1) v += __shfl_xor(v, d);
  __shared__ float r[4];
  if ((tid & 63) == 0) r[tid >> 6] = v;
  __syncthreads();
  if (tid == 0) out[0] = r[0] + r[1] + r[2] + r[3];
}

extern "C" void kernel_launch(void* const* d_in, const int* in_sizes, int n_in,
                              void* d_out, int out_size, void* d_ws, size_t ws_size,
                              hipStream_t stream) {
  (void)in_sizes; (void)n_in; (void)out_size; (void)ws_size;
  const float* feats = (const float*)d_in[0];
  const int*   tags  = (const int*)d_in[1];
  const int*   mask  = (const int*)d_in[2];
  const float* lt    = (const float*)d_in[3];
  float* per_batch = (float*)d_ws;   // 256 floats of scratch

  crf_fwd_kernel<<<BSZ, 256, 0, stream>>>(feats, tags, mask, lt, per_batch);
  crf_reduce_kernel<<<1, 256, 0, stream>>>(per_batch, (float*)d_out);
}